// Round 7
// baseline (290.835 us; speedup 1.0000x reference)
//
#include <hip/hip_runtime.h>
#include <hip/hip_cooperative_groups.h>

namespace cg = cooperative_groups;

#define T_TOK 1024
#define H_DIM 1024
#define I_DIM 768
#define E_NUM 8
#define NBLK  512

#define G13 1572864          // 8*1536*1024/8
#define G2   786432          // 8*1024*768/8
#define GX   131072
#define GZ   131072
#define GTOT (G13 + G2 + GX + GZ)   // 2621440 = 20 * NBLK*256

#define SLOT 24576           // ring slot: B 16KB + A 8KB (bf16)
#define A_OFF 16384

typedef __bf16 bf16x8 __attribute__((ext_vector_type(8)));
typedef float  f32x4  __attribute__((ext_vector_type(4)));

typedef struct {
    union { uint4 r4[3 * SLOT / 16]; float gu[64 * 132]; } u;   // 73728 B
    int tokS[64];
    int cnt[E_NUM];
} SharedBlk;                                                    // 74016 B

__device__ inline bf16x8 cvt8(float4 a, float4 b, float s) {
    bf16x8 o;
    o[0] = (__bf16)(a.x * s); o[1] = (__bf16)(a.y * s);
    o[2] = (__bf16)(a.z * s); o[3] = (__bf16)(a.w * s);
    o[4] = (__bf16)(b.x * s); o[5] = (__bf16)(b.y * s);
    o[6] = (__bf16)(b.z * s); o[7] = (__bf16)(b.w * s);
    return o;
}

__device__ inline void async16(const void* g, void* l) {
    __builtin_amdgcn_global_load_lds(
        (const __attribute__((address_space(1))) unsigned int*)g,
        (__attribute__((address_space(3))) unsigned int*)l, 16, 0, 0);
}

#define VM_WAIT12 asm volatile("s_waitcnt vmcnt(12)" ::: "memory")
#define VM_WAIT6  asm volatile("s_waitcnt vmcnt(6)"  ::: "memory")
#define VM_WAIT0  asm volatile("s_waitcnt vmcnt(0)"  ::: "memory")

#define MFMA(A, B, C) __builtin_amdgcn_mfma_f32_16x16x32_bf16(A, B, C, 0, 0, 0)

struct StgEnt { const char* p; int l; };

// ===================== phase 0: dequant + cvt + zero ======================
__device__ __forceinline__ void phase0_dev(
    int bid, int tid,
    const float* __restrict__ x,
    const float* __restrict__ w13, const float* __restrict__ w13s,
    const float* __restrict__ w2,  const float* __restrict__ w2s,
    float* __restrict__ out,
    __bf16* __restrict__ w13d, __bf16* __restrict__ w2d, __bf16* __restrict__ xbf)
{
    float4* out4 = (float4*)out;
#pragma unroll
    for (int uu = 0; uu < 20; uu++) {
        int g = uu * (NBLK * 256) + bid * 256 + tid;
        if (g < G13) {
            int k8 = g & 127;            // 128 groups per 1024-k row
            int row = g >> 7;            // e*1536 + n
            float s = w13s[(row << 3) | (k8 >> 4)];
            const float4* src = (const float4*)w13 + (size_t)g * 2;
            *(bf16x8*)(w13d + (size_t)g * 8) = cvt8(src[0], src[1], s);
        } else if (g < G13 + G2) {
            int g2 = g - G13;
            unsigned row = (unsigned)g2 / 96u;   // e*1024 + h
            int k8 = g2 - row * 96;
            float s = w2s[row * 6 + (k8 >> 4)];
            const float4* src = (const float4*)w2 + (size_t)g2 * 2;
            *(bf16x8*)(w2d + (size_t)g2 * 8) = cvt8(src[0], src[1], s);
        } else if (g < G13 + G2 + GX) {
            int gx = g - (G13 + G2);
            const float4* src = (const float4*)x + (size_t)gx * 2;
            *(bf16x8*)(xbf + (size_t)gx * 8) = cvt8(src[0], src[1], 1.0f);
        } else {
            int go = g - (G13 + G2 + GX);
            float4 z = make_float4(0.f, 0.f, 0.f, 0.f);
            out4[2 * go] = z; out4[2 * go + 1] = z;
        }
    }
}

__device__ __forceinline__ void router_dev(
    int tid, int* cnt,
    const float* __restrict__ logits,
    int* __restrict__ counts, int* __restrict__ base,
    int* __restrict__ tok_list, float* __restrict__ wt_list)
{
    if (tid < E_NUM) cnt[tid] = 0;
    __syncthreads();
#pragma unroll
    for (int tt = 0; tt < 4; tt++) {
        int t = tid + tt * 256;
        float l[E_NUM];
#pragma unroll
        for (int e = 0; e < E_NUM; e++) l[e] = logits[t * E_NUM + e];
        int e0 = 0; float m0 = l[0];
#pragma unroll
        for (int e = 1; e < E_NUM; e++) if (l[e] > m0) { m0 = l[e]; e0 = e; }
        int e1 = -1; float m1 = -3e38f;
#pragma unroll
        for (int e = 0; e < E_NUM; e++) if (e != e0 && l[e] > m1) { m1 = l[e]; e1 = e; }
        float w0 = 1.0f / (1.0f + expf(m1 - m0));
        float w1 = 1.0f - w0;
        int p0 = atomicAdd(&cnt[e0], 1);
        tok_list[e0 * T_TOK + p0] = t;
        wt_list[e0 * T_TOK + p0] = w0;
        int p1 = atomicAdd(&cnt[e1], 1);
        tok_list[e1 * T_TOK + p1] = t;
        wt_list[e1 * T_TOK + p1] = w1;
    }
    __syncthreads();
    if (tid == 0) {
        int s = 0;
        for (int e = 0; e < E_NUM; e++) { base[e] = s; counts[e] = cnt[e]; s += cnt[e]; }
    }
}

// ===================== phase 1: GEMM1 tile (M64 x N128, K=16*64) ==========
__device__ __forceinline__ void phase1_dev(
    int bx, int tid, SharedBlk* sh,
    const __bf16* __restrict__ xbf, const __bf16* __restrict__ w13d,
    const int* __restrict__ counts, const int* __restrict__ base,
    const int* __restrict__ tok_list, __bf16* __restrict__ act)
{
    const int xcd = bx & 7, t = bx >> 3;
    const int p = t % 12, m = t / 12;
    const int P = xcd + 8 * p;
    const int nb = P % 12, e = P / 12;
    const int count = counts[e];
    const int m0 = m * 64;
    if (m0 >= count) return;
    const int n0 = nb * 64;
    const int abase = base[e];
    char* ring = (char*)sh->u.r4;

    if (tid < 64) {
        int r = m0 + tid;
        sh->tokS[tid] = (r < count) ? tok_list[e * T_TOK + r] : tok_list[e * T_TOK];
    }
    __syncthreads();

    const int wv = tid >> 6, ln = tid & 63;
    StgEnt se[6];
#pragma unroll
    for (int j = 0; j < 6; j++) {
        int off = wv * 6144 + j * 1024 + ln * 16;
        se[j].l = wv * 6144 + j * 1024;
        if (off < A_OFF) {
            int r = off >> 7, sl = (off >> 4) & 7, g = sl ^ (r & 7);
            int nB = (r < 64) ? (n0 + r) : (I_DIM + n0 + r - 64);
            se[j].p = (const char*)w13d + ((size_t)e * 2 * I_DIM + nB) * 2048 + g * 16;
        } else {
            int ao = off - A_OFF, r = ao >> 7, sl = (ao >> 4) & 7, g = sl ^ (r & 7);
            se[j].p = (const char*)xbf + (size_t)sh->tokS[r] * 2048 + g * 16;
        }
    }

#define ISSUE1(kc, sb) do { \
        async16(se[0].p + (kc) * 128, (sb) + se[0].l); \
        async16(se[1].p + (kc) * 128, (sb) + se[1].l); \
        async16(se[2].p + (kc) * 128, (sb) + se[2].l); \
        async16(se[3].p + (kc) * 128, (sb) + se[3].l); \
        async16(se[4].p + (kc) * 128, (sb) + se[4].l); \
        async16(se[5].p + (kc) * 128, (sb) + se[5].l); } while (0)

    const int wid = wv, lane = ln, lrow = lane & 15, quad = lane >> 4;
    int aoff[2][4], boff[2][2];
#pragma unroll
    for (int kk = 0; kk < 2; kk++) {
        int gph = ((kk * 4 + quad) ^ (lrow & 7)) << 4;
#pragma unroll
        for (int i = 0; i < 4; i++) aoff[kk][i] = (i * 16 + lrow) * 128 + gph;
#pragma unroll
        for (int j = 0; j < 2; j++) boff[kk][j] = (wid * 32 + j * 16 + lrow) * 128 + gph;
    }

    f32x4 acc[4][2];
#pragma unroll
    for (int i = 0; i < 4; i++)
#pragma unroll
        for (int j = 0; j < 2; j++) { f32x4 z = {0.f, 0.f, 0.f, 0.f}; acc[i][j] = z; }

    auto compute = [&](const char* sb) {
        const char* Bb = sb;
        const char* Ab = sb + A_OFF;
#pragma unroll
        for (int kk = 0; kk < 2; kk++) {
            bf16x8 b0 = *(const bf16x8*)(Bb + boff[kk][0]);
            bf16x8 b1 = *(const bf16x8*)(Bb + boff[kk][1]);
#pragma unroll
            for (int i = 0; i < 4; i++) {
                bf16x8 a = *(const bf16x8*)(Ab + aoff[kk][i]);
                acc[i][0] = MFMA(a, b0, acc[i][0]);
                acc[i][1] = MFMA(a, b1, acc[i][1]);
            }
        }
    };

    VM_WAIT0;   // exact vmcnt baseline for counted waits
    ISSUE1(0, ring);
    ISSUE1(1, ring + SLOT);
#pragma unroll
    for (int k = 0; k < 16; k++) {
        if (k + 2 < 16) ISSUE1(k + 2, ring + ((k + 2) % 3) * SLOT);
        if (k < 14)       { VM_WAIT12; }
        else if (k == 14) { VM_WAIT6; }
        else              { VM_WAIT0; }
        __builtin_amdgcn_s_barrier();
        compute(ring + (k % 3) * SLOT);
        __builtin_amdgcn_s_barrier();
    }
#undef ISSUE1

    // epilogue: ring dead; reuse as gu
#pragma unroll
    for (int i = 0; i < 4; i++)
#pragma unroll
        for (int j = 0; j < 2; j++)
#pragma unroll
            for (int r = 0; r < 4; r++) {
                int mr = i * 16 + quad * 4 + r;
                int c = wid * 32 + j * 16 + lrow;
                sh->u.gu[mr * 132 + c] = acc[i][j][r];
            }
    __syncthreads();

#pragma unroll
    for (int ii = 0; ii < 16; ii++) {
        int o = ii * 256 + tid;
        int mr = o >> 6, c = o & 63;
        if (m0 + mr < count) {
            float g  = sh->u.gu[mr * 132 + c];
            float up = sh->u.gu[mr * 132 + 64 + c];
            float a  = g / (1.0f + expf(-g)) * up;
            act[(size_t)(abase + m0 + mr) * I_DIM + n0 + c] = (__bf16)a;
        }
    }
    __syncthreads();   // protect gu/ring union before next tile
}

// ===================== phase 2: GEMM2 tile (M64 x N128, K=12*64) ==========
__device__ __forceinline__ void phase2_dev(
    int bx, int tid, SharedBlk* sh,
    const __bf16* __restrict__ act, const __bf16* __restrict__ w2d,
    const int* __restrict__ counts, const int* __restrict__ base,
    const int* __restrict__ tok_list, const float* __restrict__ wt_list,
    float* __restrict__ out)
{
    const int xcd = bx & 7, t = bx >> 3;
    const int p = t & 7, m = t >> 3;
    const int P = xcd + 8 * p;
    const int nb = P & 7, e = P >> 3;     // nb == xcd
    const int count = counts[e];
    const int m0 = m * 64;
    if (m0 >= count) return;
    const int n0 = nb * 128;
    const int abase = base[e];
    char* ring = (char*)sh->u.r4;

    const int wv = tid >> 6, ln = tid & 63;
    StgEnt se[6];
#pragma unroll
    for (int j = 0; j < 6; j++) {
        int off = wv * 6144 + j * 1024 + ln * 16;
        se[j].l = wv * 6144 + j * 1024;
        if (off < A_OFF) {
            int r = off >> 7, sl = (off >> 4) & 7, g = sl ^ (r & 7);
            se[j].p = (const char*)w2d + ((size_t)e * H_DIM + n0 + r) * 1536 + g * 16;
        } else {
            int ao = off - A_OFF, r = ao >> 7, sl = (ao >> 4) & 7, g = sl ^ (r & 7);
            int gr = abase + m0 + r; if (gr > 2 * T_TOK - 1) gr = 2 * T_TOK - 1;
            se[j].p = (const char*)act + (size_t)gr * 1536 + g * 16;
        }
    }

#define ISSUE2(kc, sb) do { \
        async16(se[0].p + (kc) * 128, (sb) + se[0].l); \
        async16(se[1].p + (kc) * 128, (sb) + se[1].l); \
        async16(se[2].p + (kc) * 128, (sb) + se[2].l); \
        async16(se[3].p + (kc) * 128, (sb) + se[3].l); \
        async16(se[4].p + (kc) * 128, (sb) + se[4].l); \
        async16(se[5].p + (kc) * 128, (sb) + se[5].l); } while (0)

    const int wid = wv, lane = ln, lrow = lane & 15, quad = lane >> 4;
    int aoff[2][4], boff[2][2];
#pragma unroll
    for (int kk = 0; kk < 2; kk++) {
        int gph = ((kk * 4 + quad) ^ (lrow & 7)) << 4;
#pragma unroll
        for (int i = 0; i < 4; i++) aoff[kk][i] = (i * 16 + lrow) * 128 + gph;
#pragma unroll
        for (int j = 0; j < 2; j++) boff[kk][j] = (wid * 32 + j * 16 + lrow) * 128 + gph;
    }

    f32x4 acc[4][2];
#pragma unroll
    for (int i = 0; i < 4; i++)
#pragma unroll
        for (int j = 0; j < 2; j++) { f32x4 z = {0.f, 0.f, 0.f, 0.f}; acc[i][j] = z; }

    auto compute = [&](const char* sb) {
        const char* Bb = sb;
        const char* Ab = sb + A_OFF;
#pragma unroll
        for (int kk = 0; kk < 2; kk++) {
            bf16x8 b0 = *(const bf16x8*)(Bb + boff[kk][0]);
            bf16x8 b1 = *(const bf16x8*)(Bb + boff[kk][1]);
#pragma unroll
            for (int i = 0; i < 4; i++) {
                bf16x8 a = *(const bf16x8*)(Ab + aoff[kk][i]);
                acc[i][0] = MFMA(a, b0, acc[i][0]);
                acc[i][1] = MFMA(a, b1, acc[i][1]);
            }
        }
    };

    VM_WAIT0;
    ISSUE2(0, ring);
    ISSUE2(1, ring + SLOT);
#pragma unroll
    for (int k = 0; k < 12; k++) {
        if (k + 2 < 12) ISSUE2(k + 2, ring + ((k + 2) % 3) * SLOT);
        if (k < 10)       { VM_WAIT12; }
        else if (k == 10) { VM_WAIT6; }
        else              { VM_WAIT0; }
        __builtin_amdgcn_s_barrier();
        compute(ring + (k % 3) * SLOT);
        __builtin_amdgcn_s_barrier();
    }
#undef ISSUE2

#pragma unroll
    for (int i = 0; i < 4; i++)
#pragma unroll
        for (int r = 0; r < 4; r++) {
            int mr = i * 16 + quad * 4 + r;
            if (m0 + mr < count) {
                int   tk = tok_list[e * T_TOK + m0 + mr];
                float w  = wt_list[e * T_TOK + m0 + mr];
#pragma unroll
                for (int j = 0; j < 2; j++) {
                    int h = n0 + wid * 32 + j * 16 + lrow;
                    atomicAdd(&out[(size_t)tk * H_DIM + h], w * acc[i][j][r]);
                }
            }
        }
}

// ===================== fused cooperative kernel ===========================
__global__ __launch_bounds__(256, 2) void moe_fused(
    const float* __restrict__ x, const float* __restrict__ logits,
    const float* __restrict__ w13, const float* __restrict__ w13s,
    const float* __restrict__ w2, const float* __restrict__ w2s,
    float* __restrict__ out,
    int* counts, int* base, int* tok_list, float* wt_list,
    __bf16* act, __bf16* xbf, __bf16* w13d, __bf16* w2d)
{
    cg::grid_group grid = cg::this_grid();
    __shared__ SharedBlk sh;
    const int bid = blockIdx.x, tid = threadIdx.x;

    phase0_dev(bid, tid, x, w13, w13s, w2, w2s, out, w13d, w2d, xbf);
    if (bid == 0) router_dev(tid, sh.cnt, logits, counts, base, tok_list, wt_list);
    grid.sync();

    for (int it = 0; it < 3; ++it)
        phase1_dev(bid + NBLK * it, tid, &sh, xbf, w13d, counts, base, tok_list, act);
    grid.sync();

    for (int it = 0; it < 2; ++it)
        phase2_dev(bid + NBLK * it, tid, &sh, act, w2d, counts, base, tok_list, wt_list, out);
}

// ===================== fallback (non-cooperative) kernels =================
__global__ __launch_bounds__(256) void fb_prep(
    const float* __restrict__ x, const float* __restrict__ logits,
    const float* __restrict__ w13, const float* __restrict__ w13s,
    const float* __restrict__ w2, const float* __restrict__ w2s,
    float* __restrict__ out,
    int* counts, int* base, int* tok_list, float* wt_list,
    __bf16* xbf, __bf16* w13d, __bf16* w2d)
{
    __shared__ int cnt[E_NUM];
    phase0_dev(blockIdx.x, threadIdx.x, x, w13, w13s, w2, w2s, out, w13d, w2d, xbf);
    if (blockIdx.x == 0)
        router_dev(threadIdx.x, cnt, logits, counts, base, tok_list, wt_list);
}

__global__ __launch_bounds__(256, 2) void fb_gemm1(
    const __bf16* __restrict__ xbf, const __bf16* __restrict__ w13d,
    const int* __restrict__ counts, const int* __restrict__ base,
    const int* __restrict__ tok_list, __bf16* __restrict__ act)
{
    __shared__ SharedBlk sh;
    phase1_dev(blockIdx.x, threadIdx.x, &sh, xbf, w13d, counts, base, tok_list, act);
}

__global__ __launch_bounds__(256, 2) void fb_gemm2(
    const __bf16* __restrict__ act, const __bf16* __restrict__ w2d,
    const int* __restrict__ counts, const int* __restrict__ base,
    const int* __restrict__ tok_list, const float* __restrict__ wt_list,
    float* __restrict__ out)
{
    __shared__ SharedBlk sh;
    phase2_dev(blockIdx.x, threadIdx.x, &sh, act, w2d, counts, base, tok_list, wt_list, out);
}

extern "C" void kernel_launch(void* const* d_in, const int* in_sizes, int n_in,
                              void* d_out, int out_size, void* d_ws, size_t ws_size,
                              hipStream_t stream) {
    (void)in_sizes; (void)n_in; (void)out_size; (void)ws_size;
    const float* x      = (const float*)d_in[0];
    const float* logits = (const float*)d_in[1];
    const float* w13    = (const float*)d_in[2];
    const float* w13s   = (const float*)d_in[3];
    const float* w2     = (const float*)d_in[4];
    const float* w2s    = (const float*)d_in[5];
    float* out = (float*)d_out;

    char* ws = (char*)d_ws;
    int*    counts   = (int*)ws;                              // @0
    int*    base     = (int*)(ws + 128);                      // @128
    int*    tok_list = (int*)(ws + 256);                      // 32 KB
    float*  wt_list  = (float*)(ws + 256 + 32768);            // 32 KB
    __bf16* act      = (__bf16*)(ws + 65792);                 // 3 MB
    __bf16* xbf      = (__bf16*)(ws + 65792 + 3145728);       // 2 MB
    __bf16* w13d     = (__bf16*)(ws + 65792 + 3145728 + 2097152);            // 25.2 MB
    __bf16* w2d      = (__bf16*)(ws + 65792 + 3145728 + 2097152 + 25165824); // 12.6 MB

    void* kargs[] = { (void*)&x, (void*)&logits, (void*)&w13, (void*)&w13s,
                      (void*)&w2, (void*)&w2s, (void*)&out,
                      (void*)&counts, (void*)&base, (void*)&tok_list, (void*)&wt_list,
                      (void*)&act, (void*)&xbf, (void*)&w13d, (void*)&w2d };
    hipError_t err = hipLaunchCooperativeKernel(
        (const void*)moe_fused, dim3(NBLK), dim3(256), kargs, 0, stream);
    if (err != hipSuccess) {
        // fallback: 3-launch pipeline with identical phase bodies
        fb_prep<<<dim3(NBLK), 256, 0, stream>>>(
            x, logits, w13, w13s, w2, w2s, out,
            counts, base, tok_list, wt_list, xbf, w13d, w2d);
        fb_gemm1<<<dim3(1536), 256, 0, stream>>>(
            xbf, w13d, counts, base, tok_list, act);
        fb_gemm2<<<dim3(1024), 256, 0, stream>>>(
            act, w2d, counts, base, tok_list, wt_list, out);
    }
}

// Round 8
// 151.488 us; speedup vs baseline: 1.9199x; 1.9199x over previous
//
#include <hip/hip_runtime.h>

#define T_TOK 1024
#define H_DIM 1024
#define I_DIM 768
#define E_NUM 8

// kernelA block ranges
#define A_W13 6144           // w13 dequant blocks (G13 groups / 256)
#define A_X   512            // x convert
#define A_Z   512            // out zero
#define G13 1572864          // 8*1536*1024/8
#define G2   786432          // 8*1024*768/8

// gemm1 grid: gemm blocks then w2-dequant blocks
#define GEMM1_BLOCKS 1536    // 8 xcd * 12 pairs * 16 m-rounds
#define W2DQ_BLOCKS  3072    // G2/256

#define SLOT 24576           // ring slot: B 16KB + A 8KB
#define A_OFF 16384

typedef __bf16 bf16x8 __attribute__((ext_vector_type(8)));
typedef float  f32x4  __attribute__((ext_vector_type(4)));

__device__ inline bf16x8 cvt8(float4 a, float4 b, float s) {
    bf16x8 o;
    o[0] = (__bf16)(a.x * s); o[1] = (__bf16)(a.y * s);
    o[2] = (__bf16)(a.z * s); o[3] = (__bf16)(a.w * s);
    o[4] = (__bf16)(b.x * s); o[5] = (__bf16)(b.y * s);
    o[6] = (__bf16)(b.z * s); o[7] = (__bf16)(b.w * s);
    return o;
}

// async 16B global -> LDS (linear dest: wave-uniform base + lane*16)
__device__ inline void async16(const void* g, void* l) {
    __builtin_amdgcn_global_load_lds(
        (const __attribute__((address_space(1))) unsigned int*)g,
        (__attribute__((address_space(3))) unsigned int*)l, 16, 0, 0);
}

#define VM_WAIT6  asm volatile("s_waitcnt vmcnt(6)"  ::: "memory")
#define VM_WAIT0  asm volatile("s_waitcnt vmcnt(0)"  ::: "memory")

// ---- kernelA: w13 dequant + x -> bf16 + zero out + router ----------------
__global__ __launch_bounds__(256) void prep13_kernel(
    const float* __restrict__ w13, const float* __restrict__ w13s,
    const float* __restrict__ x,   float4* __restrict__ out4,
    __bf16* __restrict__ w13d,     __bf16* __restrict__ xbf,
    const float* __restrict__ logits,
    int* __restrict__ counts, int* __restrict__ base,
    int* __restrict__ tok_list, float* __restrict__ wt_list)
{
    const int bx = blockIdx.x;
    if (bx < A_W13) {
        int g = bx * 256 + threadIdx.x;          // < G13
        int k8 = g & 127;                        // 128 groups per 1024-k row
        int row = g >> 7;                        // e*1536 + n
        float s = w13s[(row << 3) | (k8 >> 4)];
        const float4* src = (const float4*)w13 + (size_t)g * 2;
        *(bf16x8*)(w13d + (size_t)g * 8) = cvt8(src[0], src[1], s);
        return;
    }
    if (bx < A_W13 + A_X) {
        int g = (bx - A_W13) * 256 + threadIdx.x;   // < 131072
        const float4* src = (const float4*)x + (size_t)g * 2;
        *(bf16x8*)(xbf + (size_t)g * 8) = cvt8(src[0], src[1], 1.0f);
        return;
    }
    if (bx < A_W13 + A_X + A_Z) {
        int go = (bx - A_W13 - A_X) * 256 + threadIdx.x;  // < 131072, 32B each
        float4 z = make_float4(0.f, 0.f, 0.f, 0.f);
        out4[2 * go] = z; out4[2 * go + 1] = z;
        return;
    }
    // ---- router (single block) ----
    __shared__ int cnt[E_NUM];
    const int t0 = threadIdx.x;
    if (t0 < E_NUM) cnt[t0] = 0;
    __syncthreads();
#pragma unroll
    for (int tt = 0; tt < 4; tt++) {
        int t = t0 + tt * 256;
        float l[E_NUM];
#pragma unroll
        for (int e = 0; e < E_NUM; e++) l[e] = logits[t * E_NUM + e];
        int e0 = 0; float m0 = l[0];
#pragma unroll
        for (int e = 1; e < E_NUM; e++) if (l[e] > m0) { m0 = l[e]; e0 = e; }
        int e1 = -1; float m1 = -3e38f;
#pragma unroll
        for (int e = 0; e < E_NUM; e++) if (e != e0 && l[e] > m1) { m1 = l[e]; e1 = e; }
        float w0 = 1.0f / (1.0f + expf(m1 - m0));
        float w1 = 1.0f - w0;
        int p0 = atomicAdd(&cnt[e0], 1);
        tok_list[e0 * T_TOK + p0] = t;
        wt_list[e0 * T_TOK + p0] = w0;
        int p1 = atomicAdd(&cnt[e1], 1);
        tok_list[e1 * T_TOK + p1] = t;
        wt_list[e1 * T_TOK + p1] = w1;
    }
    __syncthreads();
    if (t0 == 0) {
        int s = 0;
        for (int e = 0; e < E_NUM; e++) { base[e] = s; counts[e] = cnt[e]; s += cnt[e]; }
    }
}

#define MFMA(A, B, C) __builtin_amdgcn_mfma_f32_16x16x32_bf16(A, B, C, 0, 0, 0)

// Per-thread staging entry: global byte ptr (at K-chunk 0) + wave-uniform LDS
// byte offset within slot. Inverse-swizzled SOURCE + linear LDS dest + the
// proven swizzled ds_read offsets (both-sides-or-neither rule).
struct StgEnt { const char* p; int l; };

// ---- kernelB: GEMM1 (M=64 x N=128, BK=64) + appended w2-dequant ----------
// gload_lds staging, 2-slot LDS ring (49 KB -> 3 blocks/CU), counted vmcnt
// (never 0 in loop), raw s_barrier.
__global__ __launch_bounds__(256, 3) void gemm1_kernel(
    const __bf16* __restrict__ xbf,
    const __bf16* __restrict__ w13d,
    const int* __restrict__ counts,
    const int* __restrict__ base,
    const int* __restrict__ tok_list,
    __bf16* __restrict__ act,
    const float* __restrict__ w2,
    const float* __restrict__ w2s,
    __bf16* __restrict__ w2d)
{
    const int bx = blockIdx.x;
    if (bx >= GEMM1_BLOCKS) {
        // ---- w2 dequant (no dependency on gemm1; fills idle CUs) ----
        int g2 = (bx - GEMM1_BLOCKS) * 256 + threadIdx.x;   // < G2
        unsigned row = (unsigned)g2 / 96u;   // e*1024 + h
        int k8 = g2 - row * 96;
        float s = w2s[row * 6 + (k8 >> 4)];
        const float4* src = (const float4*)w2 + (size_t)g2 * 2;
        *(bf16x8*)(w2d + (size_t)g2 * 8) = cvt8(src[0], src[1], s);
        return;
    }

    const int xcd = bx & 7, t = bx >> 3;
    const int p = t % 12, m = t / 12;      // 12 pairs per XCD, 16 m rounds
    const int P = xcd + 8 * p;             // pair id in [0,96)
    const int nb = P % 12, e = P / 12;
    const int count = counts[e];
    const int m0 = m * 64;
    if (m0 >= count) return;
    const int n0 = nb * 64;
    const int abase = base[e];

    __shared__ union { uint4 r4[2 * SLOT / 16]; float gu[64 * 132]; } u;  // 49152 B
    __shared__ int tokS[64];
    char* ring = (char*)u.r4;

    const int tid = threadIdx.x;
    if (tid < 64) {
        int r = m0 + tid;
        tokS[tid] = (r < count) ? tok_list[e * T_TOK + r] : tok_list[e * T_TOK];
    }
    __syncthreads();   // also drains vmcnt -> clean pipeline baseline

    const int wv = tid >> 6, ln = tid & 63;
    // 6 staging calls per thread: bytes [wv*6144 + j*1024 + ln*16) of slot.
    // B region [0,16384): LDS row r (128B), slot s holds global granule s^(r&7).
    // A region [16384,24576): same per-row swizzle, rows = tokS.
    StgEnt se[6];
#pragma unroll
    for (int j = 0; j < 6; j++) {
        int off = wv * 6144 + j * 1024 + ln * 16;
        se[j].l = wv * 6144 + j * 1024;          // wave-uniform dest
        if (off < A_OFF) {
            int r = off >> 7, sl = (off >> 4) & 7, g = sl ^ (r & 7);
            int nB = (r < 64) ? (n0 + r) : (I_DIM + n0 + r - 64);
            se[j].p = (const char*)w13d + ((size_t)e * 2 * I_DIM + nB) * 2048 + g * 16;
        } else {
            int ao = off - A_OFF, r = ao >> 7, sl = (ao >> 4) & 7, g = sl ^ (r & 7);
            se[j].p = (const char*)xbf + (size_t)tokS[r] * 2048 + g * 16;
        }
    }

#define ISSUE(kc, sb) do { \
        async16(se[0].p + (kc) * 128, (sb) + se[0].l); \
        async16(se[1].p + (kc) * 128, (sb) + se[1].l); \
        async16(se[2].p + (kc) * 128, (sb) + se[2].l); \
        async16(se[3].p + (kc) * 128, (sb) + se[3].l); \
        async16(se[4].p + (kc) * 128, (sb) + se[4].l); \
        async16(se[5].p + (kc) * 128, (sb) + se[5].l); } while (0)

    const int wid = wv, lane = ln, lrow = lane & 15, quad = lane >> 4;
    int aoff[2][4], boff[2][2];
#pragma unroll
    for (int kk = 0; kk < 2; kk++) {
        int gph = ((kk * 4 + quad) ^ (lrow & 7)) << 4;
#pragma unroll
        for (int i = 0; i < 4; i++) aoff[kk][i] = (i * 16 + lrow) * 128 + gph;
#pragma unroll
        for (int j = 0; j < 2; j++) boff[kk][j] = (wid * 32 + j * 16 + lrow) * 128 + gph;
    }

    f32x4 acc[4][2];
#pragma unroll
    for (int i = 0; i < 4; i++)
#pragma unroll
        for (int j = 0; j < 2; j++) { f32x4 z = {0.f, 0.f, 0.f, 0.f}; acc[i][j] = z; }

    auto compute = [&](const char* sb) {
        const char* Bb = sb;
        const char* Ab = sb + A_OFF;
#pragma unroll
        for (int kk = 0; kk < 2; kk++) {
            bf16x8 b0 = *(const bf16x8*)(Bb + boff[kk][0]);
            bf16x8 b1 = *(const bf16x8*)(Bb + boff[kk][1]);
#pragma unroll
            for (int i = 0; i < 4; i++) {
                bf16x8 a = *(const bf16x8*)(Ab + aoff[kk][i]);
                acc[i][0] = MFMA(a, b0, acc[i][0]);
                acc[i][1] = MFMA(a, b1, acc[i][1]);
            }
        }
    };

    // pipeline: 16 K-steps, ring of 2, 1-deep prefetch.
    // Outstanding at wait point = 12 (steps k and k+1); vmcnt(6) retires step k.
    VM_WAIT0;   // exact vmcnt baseline
    ISSUE(0, ring);
#pragma unroll
    for (int k = 0; k < 16; k++) {
        if (k + 1 < 16) ISSUE(k + 1, ring + ((k + 1) & 1) * SLOT);
        if (k < 15) { VM_WAIT6; } else { VM_WAIT0; }
        __builtin_amdgcn_s_barrier();
        compute(ring + (k & 1) * SLOT);
        __builtin_amdgcn_s_barrier();
    }
#undef ISSUE

    // epilogue: ring dead; reuse as gu
#pragma unroll
    for (int i = 0; i < 4; i++)
#pragma unroll
        for (int j = 0; j < 2; j++)
#pragma unroll
            for (int r = 0; r < 4; r++) {
                int mr = i * 16 + quad * 4 + r;
                int c = wid * 32 + j * 16 + lrow;
                u.gu[mr * 132 + c] = acc[i][j][r];
            }
    __syncthreads();

#pragma unroll
    for (int ii = 0; ii < 16; ii++) {
        int o = ii * 256 + tid;
        int mr = o >> 6, c = o & 63;
        if (m0 + mr < count) {
            float g  = u.gu[mr * 132 + c];
            float up = u.gu[mr * 132 + 64 + c];
            float a  = g / (1.0f + expf(-g)) * up;
            act[(size_t)(abase + m0 + mr) * I_DIM + n0 + c] = (__bf16)a;
        }
    }
}

// ---- GEMM2: out += w * (act @ w2d^T) -------------------------------------
// M=64 x N=128, BK=64, 12 K-steps; same ring-2 gload_lds pipeline, 3/CU.
__global__ __launch_bounds__(256, 3) void gemm2_kernel(
    const __bf16* __restrict__ act,
    const __bf16* __restrict__ w2d,
    const int* __restrict__ counts,
    const int* __restrict__ base,
    const int* __restrict__ tok_list,
    const float* __restrict__ wt_list,
    float* __restrict__ out)
{
    const int bx = blockIdx.x;
    const int xcd = bx & 7, t = bx >> 3;
    const int p = t & 7, m = t >> 3;       // 8 pairs per XCD, 16 m rounds
    const int P = xcd + 8 * p;             // pair id in [0,64)
    const int nb = P & 7, e = P >> 3;      // nb == xcd: n-slice pinned per XCD
    const int count = counts[e];
    const int m0 = m * 64;
    if (m0 >= count) return;
    const int n0 = nb * 128;
    const int abase = base[e];

    __shared__ uint4 r4[2 * SLOT / 16];    // 49152 B
    char* ring = (char*)r4;

    const int tid = threadIdx.x;
    const int wv = tid >> 6, ln = tid & 63;

    StgEnt se[6];
#pragma unroll
    for (int j = 0; j < 6; j++) {
        int off = wv * 6144 + j * 1024 + ln * 16;
        se[j].l = wv * 6144 + j * 1024;
        if (off < A_OFF) {
            int r = off >> 7, sl = (off >> 4) & 7, g = sl ^ (r & 7);
            se[j].p = (const char*)w2d + ((size_t)e * H_DIM + n0 + r) * 1536 + g * 16;
        } else {
            int ao = off - A_OFF, r = ao >> 7, sl = (ao >> 4) & 7, g = sl ^ (r & 7);
            int gr = abase + m0 + r; if (gr > 2 * T_TOK - 1) gr = 2 * T_TOK - 1;
            se[j].p = (const char*)act + (size_t)gr * 1536 + g * 16;
        }
    }

#define ISSUE(kc, sb) do { \
        async16(se[0].p + (kc) * 128, (sb) + se[0].l); \
        async16(se[1].p + (kc) * 128, (sb) + se[1].l); \
        async16(se[2].p + (kc) * 128, (sb) + se[2].l); \
        async16(se[3].p + (kc) * 128, (sb) + se[3].l); \
        async16(se[4].p + (kc) * 128, (sb) + se[4].l); \
        async16(se[5].p + (kc) * 128, (sb) + se[5].l); } while (0)

    const int wid = wv, lane = ln, lrow = lane & 15, quad = lane >> 4;
    int aoff[2][4], boff[2][2];
#pragma unroll
    for (int kk = 0; kk < 2; kk++) {
        int gph = ((kk * 4 + quad) ^ (lrow & 7)) << 4;
#pragma unroll
        for (int i = 0; i < 4; i++) aoff[kk][i] = (i * 16 + lrow) * 128 + gph;
#pragma unroll
        for (int j = 0; j < 2; j++) boff[kk][j] = (wid * 32 + j * 16 + lrow) * 128 + gph;
    }

    f32x4 acc[4][2];
#pragma unroll
    for (int i = 0; i < 4; i++)
#pragma unroll
        for (int j = 0; j < 2; j++) { f32x4 z = {0.f, 0.f, 0.f, 0.f}; acc[i][j] = z; }

    auto compute = [&](const char* sb) {
        const char* Bb = sb;
        const char* Ab = sb + A_OFF;
#pragma unroll
        for (int kk = 0; kk < 2; kk++) {
            bf16x8 b0 = *(const bf16x8*)(Bb + boff[kk][0]);
            bf16x8 b1 = *(const bf16x8*)(Bb + boff[kk][1]);
#pragma unroll
            for (int i = 0; i < 4; i++) {
                bf16x8 a = *(const bf16x8*)(Ab + aoff[kk][i]);
                acc[i][0] = MFMA(a, b0, acc[i][0]);
                acc[i][1] = MFMA(a, b1, acc[i][1]);
            }
        }
    };

    // pipeline: 12 K-steps, ring of 2, 1-deep prefetch
    VM_WAIT0;
    ISSUE(0, ring);
#pragma unroll
    for (int k = 0; k < 12; k++) {
        if (k + 1 < 12) ISSUE(k + 1, ring + ((k + 1) & 1) * SLOT);
        if (k < 11) { VM_WAIT6; } else { VM_WAIT0; }
        __builtin_amdgcn_s_barrier();
        compute(ring + (k & 1) * SLOT);
        __builtin_amdgcn_s_barrier();
    }
#undef ISSUE

    // weighted atomic scatter
#pragma unroll
    for (int i = 0; i < 4; i++)
#pragma unroll
        for (int r = 0; r < 4; r++) {
            int mr = i * 16 + quad * 4 + r;
            if (m0 + mr < count) {
                int   tk = tok_list[e * T_TOK + m0 + mr];
                float w  = wt_list[e * T_TOK + m0 + mr];
#pragma unroll
                for (int j = 0; j < 2; j++) {
                    int h = n0 + wid * 32 + j * 16 + lrow;
                    atomicAdd(&out[(size_t)tk * H_DIM + h], w * acc[i][j][r]);
                }
            }
        }
}

extern "C" void kernel_launch(void* const* d_in, const int* in_sizes, int n_in,
                              void* d_out, int out_size, void* d_ws, size_t ws_size,
                              hipStream_t stream) {
    (void)in_sizes; (void)n_in; (void)out_size; (void)ws_size;
    const float* x      = (const float*)d_in[0];
    const float* logits = (const float*)d_in[1];
    const float* w13    = (const float*)d_in[2];
    const float* w13s   = (const float*)d_in[3];
    const float* w2     = (const float*)d_in[4];
    const float* w2s    = (const float*)d_in[5];
    float* out = (float*)d_out;

    char* ws = (char*)d_ws;
    int*    counts   = (int*)ws;                              // @0
    int*    base     = (int*)(ws + 128);                      // @128
    int*    tok_list = (int*)(ws + 256);                      // 32 KB
    float*  wt_list  = (float*)(ws + 256 + 32768);            // 32 KB
    __bf16* act      = (__bf16*)(ws + 65792);                 // 3 MB
    __bf16* xbf      = (__bf16*)(ws + 65792 + 3145728);       // 2 MB
    __bf16* w13d     = (__bf16*)(ws + 65792 + 3145728 + 2097152);            // 25.2 MB
    __bf16* w2d      = (__bf16*)(ws + 65792 + 3145728 + 2097152 + 25165824); // 12.6 MB

    prep13_kernel<<<dim3(A_W13 + A_X + A_Z + 1), 256, 0, stream>>>(
        w13, w13s, x, (float4*)out, w13d, xbf,
        logits, counts, base, tok_list, wt_list);
    gemm1_kernel<<<dim3(GEMM1_BLOCKS + W2DQ_BLOCKS), 256, 0, stream>>>(
        xbf, w13d, counts, base, tok_list, act, w2, w2s, w2d);
    gemm2_kernel<<<dim3(1024), 256, 0, stream>>>(
        act, w2d, counts, base, tok_list, wt_list, out);
}